// Round 1
// 110.995 us; speedup vs baseline: 1.1281x; 1.1281x over previous
//
#include <hip/hip_runtime.h>

typedef float f32x4 __attribute__((ext_vector_type(4)));
typedef float f32x16 __attribute__((ext_vector_type(16)));
typedef short s16x8 __attribute__((ext_vector_type(8)));
typedef short s16x4 __attribute__((ext_vector_type(4)));
typedef unsigned short u16;

#define NB 8
#define NC 64
#define NN 4096
#define NK 8

// float -> bf16 bits, round-to-nearest-even
__device__ __forceinline__ u16 f2bf_rne(float f) {
    unsigned u = __float_as_uint(f);
    u += 0x7FFFu + ((u >> 16) & 1u);
    return (u16)(u >> 16);
}
__device__ __forceinline__ float bf2f(u16 v) {
    return __uint_as_float(((unsigned)v) << 16);
}
// pack two f32 -> one u32 of 2 bf16 (RNE), lo = first arg
__device__ __forceinline__ unsigned cvt_pk_bf16(float lo, float hi) {
    unsigned r;
    asm("v_cvt_pk_bf16_f32 %0, %1, %2" : "=v"(r) : "v"(lo), "v"(hi));
    return r;
}
// swap: a' = {a.lanes0-31, b.lanes0-31}, b' = {a.lanes32-63, b.lanes32-63}
__device__ __forceinline__ void pl32_swap(unsigned &a, unsigned &b) {
    asm("v_permlane32_swap_b32 %0, %1" : "+v"(a), "+v"(b));
}

#define Z16 ((f32x16){0.f,0.f,0.f,0.f,0.f,0.f,0.f,0.f,0.f,0.f,0.f,0.f,0.f,0.f,0.f,0.f})

// ---------------------------------------------------------------------------
// Kernel 1: W' = [Wh(64); Wf(8); Wg(8)] (80x64) @ x[b] via MFMA.
// v2: cooperative LDS staging with f32x4 vector loads (was 96 scalar
// loads/thread, latency-bound). W' -> WL[80][72] bf16; x tile transposed ->
// XT[64n][72] bf16; fragments via ds_read_b128.
// ---------------------------------------------------------------------------
__global__ __launch_bounds__(256, 4)
void precompute_qgh(const float* __restrict__ x,
                    const float* __restrict__ Wf,
                    const float* __restrict__ Wg,
                    const float* __restrict__ Wh,
                    u16* __restrict__ Qw, u16* __restrict__ Gw,
                    u16* __restrict__ Hw)
{
    const int b  = blockIdx.y;
    const int n0 = blockIdx.x * 64;
    const int t  = threadIdx.x;
    const int wave = t >> 6, lane = t & 63, col = lane & 15, quad = lane >> 4;
    const float* xb = x + (size_t)b * NC * NN;

    __shared__ __align__(16) u16 WL[80][72];   // rows 0..63 Wh, 64..71 Wf, 72..79 Wg
    __shared__ __align__(16) u16 XT[64][72];   // x tile transposed: [n_local][c]

    // stage W' (5120 f32 = 5 x f32x4 per thread)
    #pragma unroll
    for (int r5 = 0; r5 < 5; r5++) {
        int v = r5 * 256 + t;
        int m = v >> 4, ks = (v & 15) << 2;
        const float* src = (m < 64) ? (Wh + m * 64 + ks)
                         : (m < 72) ? (Wf + (m - 64) * 64 + ks)
                                    : (Wg + (m - 72) * 64 + ks);
        f32x4 wv = *(const f32x4*)src;
        *(unsigned*)&WL[m][ks]     = (unsigned)f2bf_rne(wv[0]) | ((unsigned)f2bf_rne(wv[1]) << 16);
        *(unsigned*)&WL[m][ks + 2] = (unsigned)f2bf_rne(wv[2]) | ((unsigned)f2bf_rne(wv[3]) << 16);
    }
    // stage x tile (64c x 64n f32 = 4 x f32x4 per thread), transposed into XT
    #pragma unroll
    for (int r4 = 0; r4 < 4; r4++) {
        int v = r4 * 256 + t;
        int c = v >> 4, ns = (v & 15) << 2;
        f32x4 xv = *(const f32x4*)(xb + (size_t)c * NN + n0 + ns);
        #pragma unroll
        for (int e = 0; e < 4; e++) XT[ns + e][c] = f2bf_rne(xv[e]);
    }
    __syncthreads();

    const int n = n0 + wave * 16 + col;
    s16x8 bfrag[2], afrag[5][2];
    #pragma unroll
    for (int s = 0; s < 2; s++)
        bfrag[s] = *(const s16x8*)&XT[wave * 16 + col][s * 32 + quad * 8];
    #pragma unroll
    for (int mt = 0; mt < 5; mt++)
        #pragma unroll
        for (int s = 0; s < 2; s++)
            afrag[mt][s] = *(const s16x8*)&WL[mt * 16 + col][s * 32 + quad * 8];

    f32x4 d[5];
    #pragma unroll
    for (int mt = 0; mt < 5; mt++) d[mt] = (f32x4){0.f, 0.f, 0.f, 0.f};
    #pragma unroll
    for (int s = 0; s < 2; s++)
        #pragma unroll
        for (int mt = 0; mt < 5; mt++)
            d[mt] = __builtin_amdgcn_mfma_f32_16x16x32_bf16(afrag[mt][s], bfrag[s], d[mt], 0, 0, 0);

    // D[row=quad*4+r][col]
    u16* Hb = Hw + (size_t)b * NC * NN;
    #pragma unroll
    for (int mt = 0; mt < 4; mt++)
        #pragma unroll
        for (int r = 0; r < 4; r++)
            Hb[(size_t)(mt * 16 + quad * 4 + r) * NN + n] = f2bf_rne(d[mt][r]);
    #pragma unroll
    for (int r = 0; r < 4; r++) {
        int m = quad * 4 + r;
        u16 v = f2bf_rne(d[4][r]);
        if (m < 8) Qw[((size_t)b * NN + n) * NK + m]       = v;
        else       Gw[((size_t)b * NN + n) * NK + (m - 8)] = v;
    }
}

// ---------------------------------------------------------------------------
// Kernel 2 v2: flash attention, 32x32x16 MFMAs, P fully in-register.
// Block = 128 i-rows (4 waves x 32 i), j-chunks of 64.
// S^T = mfma(A=G[j][k], B=Q[k][i]) (K=8 zero-padded to 16): lane(hi,col)
//   holds S^T[j' = (r&3)+8*(r>>2)+4*hi][i=col] for regs r=0..15 per 32-j tile.
// P^T PV B-frags built in-register: cvt_pk pairs + permlane32_swap gives
//   B[k=hi*8+jj][n=i=col] directly (words {0,2}=swap(pk(r0,r1),pk(r4,r5)),
//   {1,3}=swap(pk(r2,r3),pk(r6,r7)), reg base 8*s2).
// V staged in LDS, 128B rows, XOR-swizzled 16B slots (swizzle pre-applied on
//   the global source; applied again on read) -> bank-conflict-free.
// Double-buffered V, ONE barrier per chunk. Row sums via ones-A MFMA on the
//   same bf16 P frags (rounding consistent between O and l).
// ---------------------------------------------------------------------------
__global__ __launch_bounds__(256, 4)
void attention_fa(const u16* __restrict__ Qw, const u16* __restrict__ Gw,
                  const u16* __restrict__ Hw,
                  u16* __restrict__ Opart, float* __restrict__ Lpart,
                  int jspan)
{
    const int b    = blockIdx.y;
    const int i0   = blockIdx.x * 128;
    const int part = blockIdx.z;
    const int t    = threadIdx.x;
    const int wave = t >> 6, lane = t & 63, col = lane & 31, hi = lane >> 5;

    __shared__ __align__(16) u16 Vl[2][64][64];   // [buf][c][swizzled j-slot]

    const u16* Qb = Qw + (size_t)b * NN * NK;
    const u16* Gb = Gw + (size_t)b * NN * NK;
    const u16* Hb = Hw + (size_t)b * NC * NN;

    // Q fragment (B-operand of S^T): B[k=hi*8+kk][n=i=col]; k>=8 zero.
    s16x8 qf;
    #pragma unroll
    for (int q = 0; q < 8; q++) ((u16*)&qf)[q] = 0;
    if (hi == 0) qf = *(const s16x8*)(Qb + (size_t)(i0 + wave * 32 + col) * NK);

    s16x8 ones;
    #pragma unroll
    for (int q = 0; q < 8; q++) ((u16*)&ones)[q] = 0x3F80;   // bf16 1.0

    f32x16 oacc[2];
    oacc[0] = Z16; oacc[1] = Z16;
    f32x16 lacc = Z16;

    const int jbase  = part * jspan;
    const int chunks = jspan / 64;
    const int vc = t >> 3, vseg = t & 7;          // staging: row vc(+32), 16B slot vseg
    const int swsl = (vseg ^ (vc & 7)) * 8;       // pre-swizzled source slot (u16)
    const int c7x8 = (col & 7) * 8;               // read-side XOR term

    s16x8 vreg0 = *(const s16x8*)(Hb + (size_t)vc * NN + jbase + swsl);
    s16x8 vreg1 = *(const s16x8*)(Hb + (size_t)(32 + vc) * NN + jbase + swsl);

    for (int cc = 0; cc < chunks; cc++) {
        const int j0 = jbase + cc * 64;
        u16* vb = &Vl[cc & 1][0][0];

        // G fragments (A-operand of S^T): A[m=j][k=hi*8+kk]; k>=8 zero.
        s16x8 ga0, ga1;
        #pragma unroll
        for (int q = 0; q < 8; q++) { ((u16*)&ga0)[q] = 0; ((u16*)&ga1)[q] = 0; }
        if (hi == 0) {
            ga0 = *(const s16x8*)(Gb + (size_t)(j0 + col) * NK);
            ga1 = *(const s16x8*)(Gb + (size_t)(j0 + 32 + col) * NK);
        }

        // stage current V chunk (linear dest), prefetch next
        // (last-iter prefetch overreads into Opart scratch — benign)
        *(s16x8*)(vb + vc * 64 + vseg * 8)        = vreg0;
        *(s16x8*)(vb + (32 + vc) * 64 + vseg * 8) = vreg1;
        vreg0 = *(const s16x8*)(Hb + (size_t)vc * NN + j0 + 64 + swsl);
        vreg1 = *(const s16x8*)(Hb + (size_t)(32 + vc) * NN + j0 + 64 + swsl);

        __syncthreads();   // V[buf] writes visible; also separates next overwrite

        #pragma unroll
        for (int jt = 0; jt < 2; jt++) {
            f32x16 S = __builtin_amdgcn_mfma_f32_32x32x16_bf16(jt ? ga1 : ga0, qf, Z16, 0, 0, 0);
            #pragma unroll
            for (int r = 0; r < 16; r++) S[r] = __expf(S[r]);
            #pragma unroll
            for (int s2 = 0; s2 < 2; s2++) {
                unsigned w0 = cvt_pk_bf16(S[8*s2+0], S[8*s2+1]);
                unsigned w2 = cvt_pk_bf16(S[8*s2+4], S[8*s2+5]);
                unsigned w1 = cvt_pk_bf16(S[8*s2+2], S[8*s2+3]);
                unsigned w3 = cvt_pk_bf16(S[8*s2+6], S[8*s2+7]);
                pl32_swap(w0, w2);   // -> bfrag words 0 and 2
                pl32_swap(w1, w3);   // -> bfrag words 1 and 3
                union { s16x8 v; unsigned u[4]; } pb;
                pb.u[0] = w0; pb.u[1] = w1; pb.u[2] = w2; pb.u[3] = w3;
                // row-sum: ones-A MFMA on same bf16 P (all regs equal Σ_j P[j][i=col])
                lacc = __builtin_amdgcn_mfma_f32_32x32x16_bf16(ones, pb.v, lacc, 0, 0, 0);
                const int soff = ((jt * 4 + s2 * 2 + hi) * 8) ^ c7x8;
                s16x8 va0 = *(const s16x8*)(vb + col * 64 + soff);
                s16x8 va1 = *(const s16x8*)(vb + (32 + col) * 64 + soff);
                oacc[0] = __builtin_amdgcn_mfma_f32_32x32x16_bf16(va0, pb.v, oacc[0], 0, 0, 0);
                oacc[1] = __builtin_amdgcn_mfma_f32_32x32x16_bf16(va1, pb.v, oacc[1], 0, 0, 0);
            }
        }
    }

    // partial row sums (duplicated across hi halves; write from hi==0)
    if (hi == 0)
        Lpart[((size_t)part * NB + b) * NN + i0 + wave * 32 + col] = lacc[0];

    // transpose O to [c][i] through LDS (reuse both V buffers = 64x128 u16)
    __syncthreads();
    u16* OT = &Vl[0][0][0];
    #pragma unroll
    for (int ct = 0; ct < 2; ct++)
        #pragma unroll
        for (int r = 0; r < 16; r++) {
            int c = ct * 32 + (r & 3) + 8 * (r >> 2) + 4 * hi;
            OT[c * 128 + wave * 32 + col] = f2bf_rne(oacc[ct][r]);
        }
    __syncthreads();
    u16* Ob = Opart + ((size_t)part * NB + b) * NC * NN;
    const int oc = t >> 2, oq = t & 3;
    #pragma unroll
    for (int e = 0; e < 4; e++)
        *(s16x8*)(Ob + (size_t)oc * NN + i0 + oq * 32 + e * 8) =
            *(const s16x8*)(OT + oc * 128 + oq * 32 + e * 8);
}

// ---------------------------------------------------------------------------
// Kernel 3: out[b,c,i] = gamma * (sum_p O_p[b,c,i]) / (sum_p l_p[b,i]) + x
// v2: Lpart loads vectorized (f32x4).
// ---------------------------------------------------------------------------
__global__ __launch_bounds__(256, 4)
void reduce_out(const u16* __restrict__ Opart, const float* __restrict__ Lpart,
                const float* __restrict__ x, const float* __restrict__ gamma,
                float* __restrict__ out, int parts)
{
    const int tid  = blockIdx.x * 256 + threadIdx.x;
    const int base = tid * 4;                 // flat over [b][c][i]
    const int bc   = base >> 12;              // b*64 + c
    const int b    = bc >> 6;
    const int ii   = base & (NN - 1);

    float s[4] = {0.f, 0.f, 0.f, 0.f};
    f32x4 l4 = (f32x4){0.f, 0.f, 0.f, 0.f};
    for (int p = 0; p < parts; p++) {
        s16x4 ov = *(const s16x4*)(Opart + ((size_t)p * NB * NC + bc) * NN + ii);
        l4 += *(const f32x4*)(Lpart + ((size_t)p * NB + b) * NN + ii);
        #pragma unroll
        for (int e = 0; e < 4; e++) s[e] += bf2f((u16)ov[e]);
    }
    const float g = gamma[0];
    const f32x4 xv = *(const f32x4*)(x + base);
    f32x4 o;
    #pragma unroll
    for (int e = 0; e < 4; e++) o[e] = g * (s[e] / l4[e]) + xv[e];
    *(f32x4*)(out + base) = o;
}

extern "C" void kernel_launch(void* const* d_in, const int* in_sizes, int n_in,
                              void* d_out, int out_size, void* d_ws, size_t ws_size,
                              hipStream_t stream) {
    const float* x     = (const float*)d_in[0];
    const float* Wf    = (const float*)d_in[1];
    const float* Wg    = (const float*)d_in[2];
    const float* Wh    = (const float*)d_in[3];
    const float* gamma = (const float*)d_in[4];
    float* out = (float*)d_out;

    u16* Qw = (u16*)d_ws;                       // [B][N][8]
    u16* Gw = Qw + (size_t)NB * NN * NK;        // [B][N][8]
    u16* Hw = Gw + (size_t)NB * NN * NK;        // [B][C][N]
    u16* Opart = Hw + (size_t)NB * NC * NN;     // [parts][B][C][N] bf16

    const size_t fixed = (size_t)(2 * NB * NN * NK + NB * NC * NN) * 2;
    int parts = 4;
    while (parts > 1) {
        size_t need = fixed + (size_t)parts * NB * NC * NN * 2
                            + (size_t)parts * NB * NN * 4 + 8192;
        if (need <= ws_size) break;
        parts >>= 1;
    }
    float* Lpart = (float*)(Opart + (size_t)parts * NB * NC * NN);
    const int jspan = NN / parts;

    precompute_qgh<<<dim3(64, NB), 256, 0, stream>>>(x, Wf, Wg, Wh, Qw, Gw, Hw);
    attention_fa<<<dim3(32, NB, parts), 256, 0, stream>>>(Qw, Gw, Hw, Opart, Lpart, jspan);
    reduce_out<<<dim3((NB * NC * NN) / 1024), 256, 0, stream>>>(Opart, Lpart, x, gamma, out, parts);
}

// Round 3
// 105.240 us; speedup vs baseline: 1.1898x; 1.0547x over previous
//
#include <hip/hip_runtime.h>

typedef float f32x4 __attribute__((ext_vector_type(4)));
typedef float f32x16 __attribute__((ext_vector_type(16)));
typedef short s16x8 __attribute__((ext_vector_type(8)));
typedef short s16x4 __attribute__((ext_vector_type(4)));
typedef unsigned short u16;

#define NB 8
#define NC 64
#define NN 4096
#define NK 8

// float -> bf16 bits, round-to-nearest-even
__device__ __forceinline__ u16 f2bf_rne(float f) {
    unsigned u = __float_as_uint(f);
    u += 0x7FFFu + ((u >> 16) & 1u);
    return (u16)(u >> 16);
}
__device__ __forceinline__ float bf2f(u16 v) {
    return __uint_as_float(((unsigned)v) << 16);
}
// pack two f32 -> one u32 of 2 bf16 (RNE), lo = first arg
__device__ __forceinline__ unsigned cvt_pk_bf16(float lo, float hi) {
    unsigned r;
    asm("v_cvt_pk_bf16_f32 %0, %1, %2" : "=v"(r) : "v"(lo), "v"(hi));
    return r;
}
// swap: a' = {a.lanes0-31, b.lanes0-31}, b' = {a.lanes32-63, b.lanes32-63}
__device__ __forceinline__ void pl32_swap(unsigned &a, unsigned &b) {
    asm("v_permlane32_swap_b32 %0, %1" : "+v"(a), "+v"(b));
}
// 2^x via the hardware transcendental unit (v_exp_f32)
__device__ __forceinline__ float exp2_hw(float x) {
    return __builtin_amdgcn_exp2f(x);
}

#define Z16 ((f32x16){0.f,0.f,0.f,0.f,0.f,0.f,0.f,0.f,0.f,0.f,0.f,0.f,0.f,0.f,0.f,0.f})

// ---------------------------------------------------------------------------
// Kernel 1: W' = [Wh(64); Wf(8); Wg(8)] (80x64) @ x[b] via MFMA.
// Cooperative LDS staging with f32x4 vector loads. W' -> WL[80][72] bf16;
// x tile transposed -> XT[64n][72] bf16; fragments via ds_read_b128.
// Wf rows pre-scaled by log2(e) so attention can use exp2 directly
// (Qw feeds only the S logits).
// ---------------------------------------------------------------------------
__global__ __launch_bounds__(256, 4)
void precompute_qgh(const float* __restrict__ x,
                    const float* __restrict__ Wf,
                    const float* __restrict__ Wg,
                    const float* __restrict__ Wh,
                    u16* __restrict__ Qw, u16* __restrict__ Gw,
                    u16* __restrict__ Hw)
{
    const int b  = blockIdx.y;
    const int n0 = blockIdx.x * 64;
    const int t  = threadIdx.x;
    const int wave = t >> 6, lane = t & 63, col = lane & 15, quad = lane >> 4;
    const float* xb = x + (size_t)b * NC * NN;

    __shared__ __align__(16) u16 WL[80][72];   // rows 0..63 Wh, 64..71 Wf, 72..79 Wg
    __shared__ __align__(16) u16 XT[64][72];   // x tile transposed: [n_local][c]

    // stage W' (5120 f32 = 5 x f32x4 per thread); Wf scaled by log2(e)
    #pragma unroll
    for (int r5 = 0; r5 < 5; r5++) {
        int v = r5 * 256 + t;
        int m = v >> 4, ks = (v & 15) << 2;
        const float* src = (m < 64) ? (Wh + m * 64 + ks)
                         : (m < 72) ? (Wf + (m - 64) * 64 + ks)
                                    : (Wg + (m - 72) * 64 + ks);
        const float scl = (m >= 64 && m < 72) ? 1.44269504088896f : 1.0f;
        f32x4 wv = *(const f32x4*)src;
        *(unsigned*)&WL[m][ks]     = (unsigned)f2bf_rne(wv[0] * scl) | ((unsigned)f2bf_rne(wv[1] * scl) << 16);
        *(unsigned*)&WL[m][ks + 2] = (unsigned)f2bf_rne(wv[2] * scl) | ((unsigned)f2bf_rne(wv[3] * scl) << 16);
    }
    // stage x tile (64c x 64n f32 = 4 x f32x4 per thread), transposed into XT
    #pragma unroll
    for (int r4 = 0; r4 < 4; r4++) {
        int v = r4 * 256 + t;
        int c = v >> 4, ns = (v & 15) << 2;
        f32x4 xv = *(const f32x4*)(xb + (size_t)c * NN + n0 + ns);
        #pragma unroll
        for (int e = 0; e < 4; e++) XT[ns + e][c] = f2bf_rne(xv[e]);
    }
    __syncthreads();

    const int n = n0 + wave * 16 + col;
    s16x8 bfrag[2], afrag[5][2];
    #pragma unroll
    for (int s = 0; s < 2; s++)
        bfrag[s] = *(const s16x8*)&XT[wave * 16 + col][s * 32 + quad * 8];
    #pragma unroll
    for (int mt = 0; mt < 5; mt++)
        #pragma unroll
        for (int s = 0; s < 2; s++)
            afrag[mt][s] = *(const s16x8*)&WL[mt * 16 + col][s * 32 + quad * 8];

    f32x4 d[5];
    #pragma unroll
    for (int mt = 0; mt < 5; mt++) d[mt] = (f32x4){0.f, 0.f, 0.f, 0.f};
    #pragma unroll
    for (int s = 0; s < 2; s++)
        #pragma unroll
        for (int mt = 0; mt < 5; mt++)
            d[mt] = __builtin_amdgcn_mfma_f32_16x16x32_bf16(afrag[mt][s], bfrag[s], d[mt], 0, 0, 0);

    // D[row=quad*4+r][col]
    u16* Hb = Hw + (size_t)b * NC * NN;
    #pragma unroll
    for (int mt = 0; mt < 4; mt++)
        #pragma unroll
        for (int r = 0; r < 4; r++)
            Hb[(size_t)(mt * 16 + quad * 4 + r) * NN + n] = f2bf_rne(d[mt][r]);
    #pragma unroll
    for (int r = 0; r < 4; r++) {
        int m = quad * 4 + r;
        u16 v = f2bf_rne(d[4][r]);
        if (m < 8) Qw[((size_t)b * NN + n) * NK + m]       = v;
        else       Gw[((size_t)b * NN + n) * NK + (m - 8)] = v;
    }
}

// ---------------------------------------------------------------------------
// Kernel 2: FULLY FUSED flash attention (reduce kernel eliminated).
// Block = 64 i-rows, 4 waves. Wave pair p = wave>>1 handles j in
// [p*2048, (p+1)*2048); within a pair, wave wi = wave&1 owns i-subtile
// [i0 + wi*32, +32). Partial (O, l) from pair 1 are combined with pair 0
// through LDS in the epilogue; normalization, gamma scale, residual add and
// f32 store are fused in-kernel.
// Per-pair V double-buffered in LDS (XOR 16B-slot swizzle, one barrier per
// chunk). S^T = mfma32(G, Q) (K=8 zero-padded to 16); P built in-register
// via cvt_pk_bf16 + permlane32_swap; row sums via ones-A MFMA on the same
// bf16 P frags. exp2 domain (log2e folded into Qw by kernel 1).
// ---------------------------------------------------------------------------
__global__ __launch_bounds__(256, 2)
void attention_fused(const u16* __restrict__ Qw, const u16* __restrict__ Gw,
                     const u16* __restrict__ Hw,
                     const float* __restrict__ x, const float* __restrict__ gamma,
                     float* __restrict__ out)
{
    const int b  = blockIdx.y;
    const int i0 = blockIdx.x * 64;
    const int t  = threadIdx.x;
    const int wave = t >> 6, lane = t & 63, col = lane & 31, hi = lane >> 5;
    const int p = wave >> 1, wi = wave & 1;

    __shared__ __align__(16) u16 Vl[2][2][64][64];   // [pair][buf][c][swizzled j-slot] = 32 KB

    const u16* Qb = Qw + (size_t)b * NN * NK;
    const u16* Gb = Gw + (size_t)b * NN * NK;
    const u16* Hb = Hw + (size_t)b * NC * NN;

    // Q fragment (B-operand of S^T): B[k=hi*8+kk][n=i=col]; k>=8 zero.
    s16x8 qf;
    #pragma unroll
    for (int q = 0; q < 8; q++) ((u16*)&qf)[q] = 0;
    if (hi == 0) qf = *(const s16x8*)(Qb + (size_t)(i0 + wi * 32 + col) * NK);

    s16x8 ones;
    #pragma unroll
    for (int q = 0; q < 8; q++) ((u16*)&ones)[q] = 0x3F80;   // bf16 1.0

    f32x16 oacc[2];
    oacc[0] = Z16; oacc[1] = Z16;
    f32x16 lacc = Z16;

    const int jbase = p * 2048;
    const int tp = t & 127;                       // thread id within pair
    const int vc = tp >> 3, vseg = tp & 7;        // staging: rows vc+16u, 16B slot vseg
    const int swsl = (vseg ^ (vc & 7)) * 8;       // pre-swizzled source slot (u16)
    const int c7x8 = (col & 7) * 8;               // read-side XOR term

    s16x8 vreg[4];
    #pragma unroll
    for (int u = 0; u < 4; u++)
        vreg[u] = *(const s16x8*)(Hb + (size_t)(vc + 16 * u) * NN + jbase + swsl);

    for (int cc = 0; cc < 32; cc++) {
        const int j0 = jbase + cc * 64;
        u16* vb = &Vl[p][cc & 1][0][0];

        // G fragments (A-operand of S^T): A[m=j][k=hi*8+kk]; k>=8 zero.
        s16x8 ga0, ga1;
        #pragma unroll
        for (int q = 0; q < 8; q++) { ((u16*)&ga0)[q] = 0; ((u16*)&ga1)[q] = 0; }
        if (hi == 0) {
            ga0 = *(const s16x8*)(Gb + (size_t)(j0 + col) * NK);
            ga1 = *(const s16x8*)(Gb + (size_t)(j0 + 32 + col) * NK);
        }

        // stage current V chunk, prefetch next (last-iter overread benign: ws tail)
        #pragma unroll
        for (int u = 0; u < 4; u++)
            *(s16x8*)(vb + (vc + 16 * u) * 64 + vseg * 8) = vreg[u];
        #pragma unroll
        for (int u = 0; u < 4; u++)
            vreg[u] = *(const s16x8*)(Hb + (size_t)(vc + 16 * u) * NN + j0 + 64 + swsl);

        __syncthreads();   // V[buf] writes visible; separates reuse of same buf

        #pragma unroll
        for (int jt = 0; jt < 2; jt++) {
            f32x16 S = __builtin_amdgcn_mfma_f32_32x32x16_bf16(jt ? ga1 : ga0, qf, Z16, 0, 0, 0);
            #pragma unroll
            for (int r = 0; r < 16; r++) S[r] = exp2_hw(S[r]);
            #pragma unroll
            for (int s2 = 0; s2 < 2; s2++) {
                unsigned w0 = cvt_pk_bf16(S[8*s2+0], S[8*s2+1]);
                unsigned w2 = cvt_pk_bf16(S[8*s2+4], S[8*s2+5]);
                unsigned w1 = cvt_pk_bf16(S[8*s2+2], S[8*s2+3]);
                unsigned w3 = cvt_pk_bf16(S[8*s2+6], S[8*s2+7]);
                pl32_swap(w0, w2);   // -> bfrag words 0 and 2
                pl32_swap(w1, w3);   // -> bfrag words 1 and 3
                union { s16x8 v; unsigned u[4]; } pb;
                pb.u[0] = w0; pb.u[1] = w1; pb.u[2] = w2; pb.u[3] = w3;
                // row-sum: ones-A MFMA on same bf16 P (all regs = Σ_j P[j][i=col])
                lacc = __builtin_amdgcn_mfma_f32_32x32x16_bf16(ones, pb.v, lacc, 0, 0, 0);
                const int soff = ((jt * 4 + s2 * 2 + hi) * 8) ^ c7x8;
                s16x8 va0 = *(const s16x8*)(vb + col * 64 + soff);
                s16x8 va1 = *(const s16x8*)(vb + (32 + col) * 64 + soff);
                oacc[0] = __builtin_amdgcn_mfma_f32_32x32x16_bf16(va0, pb.v, oacc[0], 0, 0, 0);
                oacc[1] = __builtin_amdgcn_mfma_f32_32x32x16_bf16(va1, pb.v, oacc[1], 0, 0, 0);
            }
        }
    }

    // ---- epilogue: cross-pair combine, normalize, gamma, residual, store ----
    float* Of = (float*)&Vl[0][0][0][0];          // [2][64][32] f32 = 16 KB
    float* Lf = Of + 2 * 64 * 32;                 // 64 f32
    u16*  OT  = (u16*)(Lf + 64);                  // [64][64] bf16 swizzled = 8 KB
    const float g = gamma[0];

    __syncthreads();                              // all V-LDS reads complete
    if (p == 1) {
        #pragma unroll
        for (int ct = 0; ct < 2; ct++)
            #pragma unroll
            for (int r = 0; r < 16; r++) {
                int c = ct * 32 + (r & 3) + 8 * (r >> 2) + 4 * hi;
                Of[(wi * 64 + c) * 32 + col] = oacc[ct][r];
            }
        if (hi == 0) Lf[wi * 32 + col] = lacc[0];
    }
    __syncthreads();
    if (p == 0) {
        const float scale = g / (lacc[0] + Lf[wi * 32 + col]);
        const int i = wi * 32 + col;
        #pragma unroll
        for (int ct = 0; ct < 2; ct++)
            #pragma unroll
            for (int r = 0; r < 16; r++) {
                int c = ct * 32 + (r & 3) + 8 * (r >> 2) + 4 * hi;
                float o = (oacc[ct][r] + Of[(wi * 64 + c) * 32 + col]) * scale;
                OT[c * 64 + (((i >> 3) ^ (c & 7)) << 3) + (i & 7)] = f2bf_rne(o);
            }
    }
    __syncthreads();

    const int oc = t >> 2, q4 = t & 3;
    s16x8 v0 = *(const s16x8*)&OT[oc * 64 + (((2 * q4)     ^ (oc & 7)) << 3)];
    s16x8 v1 = *(const s16x8*)&OT[oc * 64 + (((2 * q4 + 1) ^ (oc & 7)) << 3)];
    const float* xr = x   + ((size_t)b * NC + oc) * NN + i0 + q4 * 16;
    float*      orow = out + ((size_t)b * NC + oc) * NN + i0 + q4 * 16;
    #pragma unroll
    for (int e = 0; e < 4; e++) {
        f32x4 xv = *(const f32x4*)(xr + e * 4);
        f32x4 ov;
        #pragma unroll
        for (int k = 0; k < 4; k++) {
            u16 val = (e < 2) ? (u16)((u16*)&v0)[e * 4 + k]
                              : (u16)((u16*)&v1)[(e - 2) * 4 + k];
            ov[k] = bf2f(val) + xv[k];
        }
        *(f32x4*)(orow + e * 4) = ov;
    }
}

extern "C" void kernel_launch(void* const* d_in, const int* in_sizes, int n_in,
                              void* d_out, int out_size, void* d_ws, size_t ws_size,
                              hipStream_t stream) {
    const float* x     = (const float*)d_in[0];
    const float* Wf    = (const float*)d_in[1];
    const float* Wg    = (const float*)d_in[2];
    const float* Wh    = (const float*)d_in[3];
    const float* gamma = (const float*)d_in[4];
    float* out = (float*)d_out;

    u16* Qw = (u16*)d_ws;                       // [B][N][8]
    u16* Gw = Qw + (size_t)NB * NN * NK;        // [B][N][8]
    u16* Hw = Gw + (size_t)NB * NN * NK;        // [B][C][N]

    precompute_qgh<<<dim3(64, NB), 256, 0, stream>>>(x, Wf, Wg, Wh, Qw, Gw, Hw);
    attention_fused<<<dim3(64, NB), 256, 0, stream>>>(Qw, Gw, Hw, x, gamma, out);
}